// Round 12
// baseline (110.651 us; speedup 1.0000x reference)
//
#include <hip/hip_runtime.h>
#include <math.h>

#define N_NODES 50000
#define N_EDGES 1200000
#define IN_DIM  256
#define OUT_DIM 64
#define SLOPE   0.2f
#define BNODES  64           // nodes per bucket: b = dst>>6, dl = dst&63
#define NBKT    782          // ceil(50000/64)
#define NBKT_PAD 1024
#define EPB     1024         // edges per k_bin chunk
#define NCHUNK  1172         // ceil(1200000/1024)
#define BCAP    2048         // max raw edges per bucket (mean 1536, +13 sigma)
#define SSTRIDE 2496         // padded srcEx stride per bucket (BCAP + 64*7, x8)

typedef unsigned int   uint;
typedef unsigned short ushort;
typedef float  f32x4  __attribute__((ext_vector_type(4)));
typedef short  short8 __attribute__((ext_vector_type(8)));

__device__ inline ushort bf16_rne(float f) {
    uint u = __float_as_uint(f);
    u += 0x7FFF + ((u >> 16) & 1);
    return (ushort)(u >> 16);
}
__device__ inline float bf16_f32(ushort s) {
    return __uint_as_float(((uint)s) << 16);
}
__device__ inline ushort f32_f16(float f) {
    _Float16 h = (_Float16)f;
    return __builtin_bit_cast(ushort, h);
}
__device__ inline float f16_f32(ushort u) {
    return (float)__builtin_bit_cast(_Float16, u);
}

// ---------------------------------------------------------------------------
// K0: blocks 0..NCHUNK-1: per-chunk bucket-grouping of 1024 edges (block-major
// output, NO global placement/atomics). binned[c*EPB+i] = (dl<<16)|src grouped
// by bucket; tab[c*1024+b] = (localOffset<<11)|count.
// Blocks NCHUNK..NCHUNK+63: W -> bf16 hi/lo prep.
// ---------------------------------------------------------------------------
__global__ __launch_bounds__(256) void k_binprep(const int* __restrict__ src,
                                                 const int* __restrict__ dst,
                                                 const float* __restrict__ Wfc,
                                                 ushort* __restrict__ Whi,
                                                 ushort* __restrict__ Wlo,
                                                 uint* __restrict__ binned,
                                                 uint* __restrict__ tab) {
    if (blockIdx.x >= NCHUNK) {
        int i = (blockIdx.x - NCHUNK) * 256 + threadIdx.x;
        float f = Wfc[i];
        ushort hi = bf16_rne(f);
        Whi[i] = hi;
        Wlo[i] = bf16_rne(f - bf16_f32(hi));
        return;
    }
    __shared__ uint staged[EPB];           // 4 KB
    __shared__ int lhist[NBKT_PAD];        // 4 KB
    __shared__ int lcur[NBKT_PAD];         // 4 KB
    __shared__ int ws[256];
    const int t = threadIdx.x;
    const int c = blockIdx.x;
    const int base = c * EPB;
    const int n = min(EPB, N_EDGES - base);   // multiple of 4

    ((int4*)lhist)[t] = int4{0, 0, 0, 0};
    __syncthreads();

    int4 d4, s4;
    bool act = (4 * t < n);
    if (act) {
        d4 = ((const int4*)(dst + base))[t];
        s4 = ((const int4*)(src + base))[t];
        atomicAdd(&lhist[d4.x >> 6], 1);
        atomicAdd(&lhist[d4.y >> 6], 1);
        atomicAdd(&lhist[d4.z >> 6], 1);
        atomicAdd(&lhist[d4.w >> 6], 1);
    }
    __syncthreads();

    int4 hv = ((const int4*)lhist)[t];
    int lsum = hv.x + hv.y + hv.z + hv.w;
    ws[t] = lsum; __syncthreads();
    #pragma unroll
    for (int off = 1; off < 256; off <<= 1) {
        int x = (t >= off) ? ws[t - off] : 0;
        __syncthreads(); ws[t] += x; __syncthreads();
    }
    int excl = ws[t] - lsum;
    int p0 = excl, p1 = p0 + hv.x, p2 = p1 + hv.y, p3 = p2 + hv.z;
    lcur[4 * t]     = p0;
    lcur[4 * t + 1] = p1;
    lcur[4 * t + 2] = p2;
    lcur[4 * t + 3] = p3;
    uint4 te;
    te.x = ((uint)p0 << 11) | (uint)hv.x;
    te.y = ((uint)p1 << 11) | (uint)hv.y;
    te.z = ((uint)p2 << 11) | (uint)hv.z;
    te.w = ((uint)p3 << 11) | (uint)hv.w;
    ((uint4*)(tab + (size_t)c * NBKT_PAD))[t] = te;
    __syncthreads();

    if (act) {
        int dd[4] = {d4.x, d4.y, d4.z, d4.w};
        int ss[4] = {s4.x, s4.y, s4.z, s4.w};
        #pragma unroll
        for (int u = 0; u < 4; ++u) {
            int b = dd[u] >> 6, dl = dd[u] & 63;
            int slot = atomicAdd(&lcur[b], 1);
            staged[slot] = ((uint)dl << 16) | (uint)ss[u];
        }
    }
    __syncthreads();
    #pragma unroll
    for (int k = 0; k < EPB / 256; ++k) {
        int i = k * 256 + t;
        if (i < n) binned[base + i] = staged[i];
    }
}

// ---------------------------------------------------------------------------
// K1: z = h @ W^T via mfma_f32_16x16x32_bf16, split-bf16 (hihi + lohi + hilo).
// One wave / 16 nodes, no LDS. Fused sS/sD. z stored f16 in TWO 3.2MB halves
// (dims 0-31 -> zlo, 32-63 -> zhi) so each aggc pass is L2-resident.
// ---------------------------------------------------------------------------
__global__ __launch_bounds__(64) void k_gemm(const float* __restrict__ h,
                                             const ushort* __restrict__ Whi,
                                             const ushort* __restrict__ Wlo,
                                             const float* __restrict__ Wattn,
                                             ushort* __restrict__ zlo,
                                             ushort* __restrict__ zhi,
                                             float* __restrict__ sS,
                                             float* __restrict__ sD) {
    const int l   = threadIdx.x;
    const int r16 = l & 15;
    const int g   = l >> 4;
    const int base = blockIdx.x * 16;

    const float*  ha = h   + (size_t)(base + r16) * IN_DIM + g * 8;
    const ushort* wh = Whi + (size_t)r16 * IN_DIM + g * 8;
    const ushort* wl = Wlo + (size_t)r16 * IN_DIM + g * 8;

    f32x4 c[4] = {{0,0,0,0},{0,0,0,0},{0,0,0,0},{0,0,0,0}};

    #pragma unroll
    for (int ks = 0; ks < 8; ++ks) {
        float4 a0 = *(const float4*)(ha + ks * 32);
        float4 a1 = *(const float4*)(ha + ks * 32 + 4);
        float af[8] = {a0.x, a0.y, a0.z, a0.w, a1.x, a1.y, a1.z, a1.w};
        short8 ahi, alo;
        #pragma unroll
        for (int i = 0; i < 8; ++i) {
            ushort hi = bf16_rne(af[i]);
            ahi[i] = (short)hi;
            alo[i] = (short)bf16_rne(af[i] - bf16_f32(hi));
        }
        #pragma unroll
        for (int n = 0; n < 4; ++n) {
            short8 bh = *(const short8*)(wh + n * 16 * IN_DIM + ks * 32);
            short8 bl = *(const short8*)(wl + n * 16 * IN_DIM + ks * 32);
            c[n] = __builtin_amdgcn_mfma_f32_16x16x32_bf16(ahi, bh, c[n], 0, 0, 0);
            c[n] = __builtin_amdgcn_mfma_f32_16x16x32_bf16(alo, bh, c[n], 0, 0, 0);
            c[n] = __builtin_amdgcn_mfma_f32_16x16x32_bf16(ahi, bl, c[n], 0, 0, 0);
        }
    }

    float aSv[4], aDv[4];
    #pragma unroll
    for (int n = 0; n < 4; ++n) {
        aSv[n] = Wattn[n * 16 + r16];
        aDv[n] = Wattn[OUT_DIM + n * 16 + r16];
    }
    #pragma unroll
    for (int r = 0; r < 4; ++r) {
        int node = base + g * 4 + r;
        float ss = 0.f, sd = 0.f;
        #pragma unroll
        for (int n = 0; n < 4; ++n) {
            float v = c[n][r];
            ushort hv16 = f32_f16(v);
            if (n < 2) zlo[(size_t)node * 32 + n * 16 + r16] = hv16;
            else       zhi[(size_t)node * 32 + (n - 2) * 16 + r16] = hv16;
            ss += v * aSv[n];
            sd += v * aDv[n];
        }
        ss += __shfl_xor(ss, 1); ss += __shfl_xor(ss, 2);
        ss += __shfl_xor(ss, 4); ss += __shfl_xor(ss, 8);
        sd += __shfl_xor(sd, 1); sd += __shfl_xor(sd, 2);
        sd += __shfl_xor(sd, 4); sd += __shfl_xor(sd, 8);
        if (r16 == 0) { sS[node] = ss; sD[node] = sd; }
    }
}

// ---------------------------------------------------------------------------
// K2: per-64-node-bucket sort. Gathers bucket edges from NCHUNK block-major
// runs via tab, stages in LDS, counting-sorts by dl with fused exp (f16),
// writes srcEx with x8-padded node segments; pad slots are DUMMY edges
// (src=0, ex=0) so aggc is tail-free. cntArr stores PADDED count.
// ---------------------------------------------------------------------------
__global__ __launch_bounds__(256) void k_sort(const uint* __restrict__ binned,
                                              const uint* __restrict__ tab,
                                              const float* __restrict__ sS,
                                              const float* __restrict__ sD,
                                              uint* __restrict__ srcEx,
                                              int* __restrict__ rowptrFine,
                                              int* __restrict__ cntArr) {
    __shared__ uint lstage[BCAP];          // 8 KB
    __shared__ uint lEdge[SSTRIDE];        // 9.75 KB
    __shared__ int lhist[64], lcur[64], ws[256];
    __shared__ float ldsD[64];
    __shared__ int sPtot;
    const int b = blockIdx.x, t = threadIdx.x;
    const int node = (b << 6) + t;
    if (t < 64) {
        lhist[t] = 0;
        ldsD[t] = (node < N_NODES) ? sD[node] : 0.f;
    }
    __syncthreads();

    // pass 1: walk my chunks' tab entries, count my edges
    uint runs[5];
    int nck = 0, myCnt = 0;
    for (int c = t; c < NCHUNK; c += 256) {
        uint e = tab[(size_t)c * NBKT_PAD + b];
        runs[nck++] = e;
        myCnt += (int)(e & 0x7FF);
    }
    ws[t] = myCnt; __syncthreads();
    #pragma unroll
    for (int off = 1; off < 256; off <<= 1) {
        int x = (t >= off) ? ws[t - off] : 0;
        __syncthreads(); ws[t] += x; __syncthreads();
    }
    int pos = ws[t] - myCnt;
    int n = ws[255];
    __syncthreads();

    // pass 2: gather my runs into lstage + dl histogram
    {
        int k = 0;
        for (int c = t; c < NCHUNK; c += 256, ++k) {
            uint e = runs[k];
            int cnt = (int)(e & 0x7FF);
            const uint* pB = binned + (size_t)c * EPB + (e >> 11);
            for (int i = 0; i < cnt; ++i) {
                uint w = pB[i];
                lstage[pos++] = w;
                atomicAdd(&lhist[w >> 16], 1);
            }
        }
    }
    __syncthreads();

    // pad-to-x8 scan over 64 nodes; zero-fill dummy pad slots
    int pc = 0;
    if (t < 64) { pc = (lhist[t] + 7) & ~7; ws[t] = pc; }
    __syncthreads();
    #pragma unroll
    for (int off = 1; off < 64; off <<= 1) {
        int x = 0;
        if (t < 64 && t >= off) x = ws[t - off];
        __syncthreads();
        if (t < 64) ws[t] += x;
        __syncthreads();
    }
    if (t < 64) {
        int pexcl = ws[t] - pc;
        lcur[t] = pexcl;
        for (int j = lhist[t]; j < pc; ++j) lEdge[pexcl + j] = 0;  // dummy: src=0, ex=0
        if (node < N_NODES) {
            rowptrFine[node] = b * SSTRIDE + pexcl;
            cntArr[node] = pc;            // padded count (multiple of 8)
        }
        if (t == 63) sPtot = ws[63];
    }
    __syncthreads();

    // permute + fused exp
    for (int i = t; i < n; i += 256) {
        uint w = lstage[i];
        int dl = (int)(w >> 16);
        int s  = (int)(w & 0xFFFF);
        float e = sS[s] + ldsD[dl];
        e = e > 0.f ? e : SLOPE * e;
        ushort exb = f32_f16(__expf(e));
        int slot = atomicAdd(&lcur[dl], 1);
        lEdge[slot] = ((w & 0xFFFFu) << 16) | (uint)exb;
    }
    __syncthreads();

    int ptot = sPtot;
    uint* dstp = srcEx + (size_t)b * SSTRIDE;
    for (int i = t; i < ptot; i += 256) dstp[i] = lEdge[i];
}

// ---------------------------------------------------------------------------
// K3: half-dim aggregation pass. One wave per dst node; 8 lanes/edge, lane
// covers 4 dims of a 32-dim half-row via one uint2 (8B) gather -> one gather
// instr serves 8 edges, all from an L2-RESIDENT 3.2MB half-array. Tail-free
// (x8 dummy padding); 3-round shfl reduce; float4 store into out half.
// ---------------------------------------------------------------------------
__global__ __launch_bounds__(256) void k_aggc(const uint2* __restrict__ zrowH,
                                              const uint* __restrict__ srcEx,
                                              const int* __restrict__ rowptr,
                                              const int* __restrict__ cntArr,
                                              float* __restrict__ out,
                                              int halfSel) {
    int node = blockIdx.x * 4 + (threadIdx.x >> 6);
    int lane = threadIdx.x & 63;
    int oct = lane >> 3, ql = lane & 7;
    int beg = rowptr[node];
    int cnt8 = cntArr[node];
    float a0 = 0.f, a1 = 0.f, a2 = 0.f, a3 = 0.f, den = 0.f;
    #pragma unroll 4
    for (int i = 0; i < cnt8; i += 8) {
        uint w = srcEx[beg + i + oct];
        uint2 zp = zrowH[((w >> 16) << 3) + ql];
        float ex = f16_f32((ushort)(w & 0xFFFF));
        a0 += ex * f16_f32((ushort)(zp.x & 0xFFFF));
        a1 += ex * f16_f32((ushort)(zp.x >> 16));
        a2 += ex * f16_f32((ushort)(zp.y & 0xFFFF));
        a3 += ex * f16_f32((ushort)(zp.y >> 16));
        den += ex;
    }
    a0 += __shfl_xor(a0, 8); a0 += __shfl_xor(a0, 16); a0 += __shfl_xor(a0, 32);
    a1 += __shfl_xor(a1, 8); a1 += __shfl_xor(a1, 16); a1 += __shfl_xor(a1, 32);
    a2 += __shfl_xor(a2, 8); a2 += __shfl_xor(a2, 16); a2 += __shfl_xor(a2, 32);
    a3 += __shfl_xor(a3, 8); a3 += __shfl_xor(a3, 16); a3 += __shfl_xor(a3, 32);
    den += __shfl_xor(den, 8); den += __shfl_xor(den, 16); den += __shfl_xor(den, 32);
    if (oct == 0) {
        float inv = den > 0.f ? 1.f / den : 0.f;
        float r0 = a0 * inv, r1 = a1 * inv, r2 = a2 * inv, r3 = a3 * inv;
        r0 = r0 > 0.f ? r0 : expm1f(r0);
        r1 = r1 > 0.f ? r1 : expm1f(r1);
        r2 = r2 > 0.f ? r2 : expm1f(r2);
        r3 = r3 > 0.f ? r3 : expm1f(r3);
        float4 r = make_float4(r0, r1, r2, r3);
        ((float4*)out)[(size_t)node * 16 + halfSel * 8 + ql] = r;
    }
}

static inline char* alignup(char* p) {
    return (char*)(((uintptr_t)p + 63) & ~(uintptr_t)63);
}

extern "C" void kernel_launch(void* const* d_in, const int* in_sizes, int n_in,
                              void* d_out, int out_size, void* d_ws, size_t ws_size,
                              hipStream_t stream) {
    const float* h     = (const float*)d_in[0];
    const float* Wfc   = (const float*)d_in[1];
    const float* Wattn = (const float*)d_in[2];
    const int*   src   = (const int*)d_in[3];
    const int*   dst   = (const int*)d_in[4];
    float* out = (float*)d_out;

    // workspace layout (64B-aligned regions)
    char* p = (char*)d_ws;
    uint*   binned  = (uint*)p;   p = alignup(p + (size_t)N_EDGES * 4);
    uint*   tab     = (uint*)p;   p = alignup(p + (size_t)NCHUNK * NBKT_PAD * 4);
    uint*   srcEx   = (uint*)p;   p = alignup(p + (size_t)NBKT * SSTRIDE * 4);
    int*    rowptrF = (int*)p;    p = alignup(p + (size_t)N_NODES * 4);
    int*    cntArr  = (int*)p;    p = alignup(p + (size_t)N_NODES * 4);
    float*  sS      = (float*)p;  p = alignup(p + (size_t)N_NODES * 4);
    float*  sD      = (float*)p;  p = alignup(p + (size_t)N_NODES * 4);
    ushort* Whi     = (ushort*)p; p = alignup(p + OUT_DIM * IN_DIM * 2);
    ushort* Wlo     = (ushort*)p; p = alignup(p + OUT_DIM * IN_DIM * 2);
    ushort* zlo     = (ushort*)p; p = alignup(p + (size_t)N_NODES * 32 * 2);
    ushort* zhi     = (ushort*)p;

    k_binprep<<<NCHUNK + 64, 256, 0, stream>>>(src, dst, Wfc, Whi, Wlo, binned, tab);
    k_gemm<<<N_NODES / 16, 64, 0, stream>>>(h, Whi, Wlo, Wattn, zlo, zhi, sS, sD);
    k_sort<<<NBKT, 256, 0, stream>>>(binned, tab, sS, sD, srcEx, rowptrF, cntArr);
    k_aggc<<<N_NODES / 4, 256, 0, stream>>>((const uint2*)zlo, srcEx, rowptrF, cntArr, out, 0);
    k_aggc<<<N_NODES / 4, 256, 0, stream>>>((const uint2*)zhi, srcEx, rowptrF, cntArr, out, 1);
}

// Round 13
// 109.620 us; speedup vs baseline: 1.0094x; 1.0094x over previous
//
#include <hip/hip_runtime.h>
#include <math.h>

#define N_NODES 50000
#define N_EDGES 1200000
#define IN_DIM  256
#define OUT_DIM 64
#define SLOPE   0.2f
#define BNODES  64           // nodes per bucket: b = dst>>6, dl = dst&63
#define NBKT    782          // ceil(50000/64)
#define NBKT_PAD 1024
#define EPB     1024         // edges per k_bin chunk
#define NCHUNK  1172         // ceil(1200000/1024)
#define NGEMMB  782          // gemm blocks (64 nodes each, 4 waves x 16)
#define BCAP    2048         // max raw edges per bucket (mean 1536, +13 sigma)
#define SSTRIDE 2240         // padded srcEx stride per bucket (BCAP + 64*3, x4)

typedef unsigned int   uint;
typedef unsigned short ushort;
typedef float  f32x4  __attribute__((ext_vector_type(4)));
typedef short  short8 __attribute__((ext_vector_type(8)));

__device__ inline ushort bf16_rne(float f) {
    uint u = __float_as_uint(f);
    u += 0x7FFF + ((u >> 16) & 1);
    return (ushort)(u >> 16);
}
__device__ inline float bf16_f32(ushort s) {
    return __uint_as_float(((uint)s) << 16);
}
__device__ inline ushort f32_f16(float f) {
    _Float16 h = (_Float16)f;
    return __builtin_bit_cast(ushort, h);
}
__device__ inline float f16_f32(ushort u) {
    return (float)__builtin_bit_cast(_Float16, u);
}

// ---------------------------------------------------------------------------
// K0: W -> bf16 hi/lo split (runs first; k_binmm's gemm blocks consume it)
// ---------------------------------------------------------------------------
__global__ __launch_bounds__(256) void k_wprep(const float* __restrict__ Wfc,
                                               ushort* __restrict__ Whi,
                                               ushort* __restrict__ Wlo) {
    int i = blockIdx.x * 256 + threadIdx.x;
    if (i >= OUT_DIM * IN_DIM) return;
    float f = Wfc[i];
    ushort hi = bf16_rne(f);
    Whi[i] = hi;
    Wlo[i] = bf16_rne(f - bf16_f32(hi));
}

// ---------------------------------------------------------------------------
// K1: merged independent phases in ONE launch:
//  blocks [0, NCHUNK): per-chunk bucket-grouping (block-major binned + tab)
//  blocks [NCHUNK, NCHUNK+NGEMMB): z = h @ W^T (MFMA, A=bf16-hi only,
//    W = precomputed hi+lo => 2 MFMAs), 4 waves x 16 nodes; fused sS/sD;
//    z stored f16.
// The two phases have disjoint bottlenecks (LDS scan/atomics vs HBM+MFMA)
// and overlap across CUs.
// ---------------------------------------------------------------------------
__global__ __launch_bounds__(256) void k_binmm(const int* __restrict__ src,
                                               const int* __restrict__ dst,
                                               const float* __restrict__ h,
                                               const ushort* __restrict__ Whi,
                                               const ushort* __restrict__ Wlo,
                                               const float* __restrict__ Wattn,
                                               uint* __restrict__ binned,
                                               uint* __restrict__ tab,
                                               ushort* __restrict__ zh,
                                               float* __restrict__ sS,
                                               float* __restrict__ sD) {
    if (blockIdx.x >= NCHUNK) {
        // ---------------- GEMM phase ----------------
        const int gb  = blockIdx.x - NCHUNK;
        const int wid = threadIdx.x >> 6;
        const int l   = threadIdx.x & 63;
        const int r16 = l & 15;
        const int g   = l >> 4;
        const int base = gb * 64 + wid * 16;

        int arow = base + r16;
        if (arow >= N_NODES) arow = N_NODES - 1;   // clamp (outputs discarded)
        const float*  ha = h   + (size_t)arow * IN_DIM + g * 8;
        const ushort* wh = Whi + (size_t)r16 * IN_DIM + g * 8;
        const ushort* wl = Wlo + (size_t)r16 * IN_DIM + g * 8;

        f32x4 c[4] = {{0,0,0,0},{0,0,0,0},{0,0,0,0},{0,0,0,0}};

        #pragma unroll
        for (int ks = 0; ks < 8; ++ks) {
            float4 a0 = *(const float4*)(ha + ks * 32);
            float4 a1 = *(const float4*)(ha + ks * 32 + 4);
            float af[8] = {a0.x, a0.y, a0.z, a0.w, a1.x, a1.y, a1.z, a1.w};
            short8 ahi;
            #pragma unroll
            for (int i = 0; i < 8; ++i) ahi[i] = (short)bf16_rne(af[i]);
            #pragma unroll
            for (int n = 0; n < 4; ++n) {
                short8 bh = *(const short8*)(wh + n * 16 * IN_DIM + ks * 32);
                short8 bl = *(const short8*)(wl + n * 16 * IN_DIM + ks * 32);
                c[n] = __builtin_amdgcn_mfma_f32_16x16x32_bf16(ahi, bh, c[n], 0, 0, 0);
                c[n] = __builtin_amdgcn_mfma_f32_16x16x32_bf16(ahi, bl, c[n], 0, 0, 0);
            }
        }

        float aSv[4], aDv[4];
        #pragma unroll
        for (int n = 0; n < 4; ++n) {
            aSv[n] = Wattn[n * 16 + r16];
            aDv[n] = Wattn[OUT_DIM + n * 16 + r16];
        }
        #pragma unroll
        for (int r = 0; r < 4; ++r) {
            int node = base + g * 4 + r;
            float ss = 0.f, sd = 0.f;
            #pragma unroll
            for (int n = 0; n < 4; ++n) {
                float v = c[n][r];
                if (node < N_NODES)
                    zh[(size_t)node * OUT_DIM + n * 16 + r16] = f32_f16(v);
                ss += v * aSv[n];
                sd += v * aDv[n];
            }
            ss += __shfl_xor(ss, 1); ss += __shfl_xor(ss, 2);
            ss += __shfl_xor(ss, 4); ss += __shfl_xor(ss, 8);
            sd += __shfl_xor(sd, 1); sd += __shfl_xor(sd, 2);
            sd += __shfl_xor(sd, 4); sd += __shfl_xor(sd, 8);
            if (r16 == 0 && node < N_NODES) { sS[node] = ss; sD[node] = sd; }
        }
        return;
    }

    // ---------------- BINPREP phase ----------------
    __shared__ uint staged[EPB];           // 4 KB
    __shared__ int lhist[NBKT_PAD];        // 4 KB
    __shared__ int lcur[NBKT_PAD];         // 4 KB
    __shared__ int ws[256];
    const int t = threadIdx.x;
    const int c = blockIdx.x;
    const int base = c * EPB;
    const int n = min(EPB, N_EDGES - base);   // multiple of 4

    ((int4*)lhist)[t] = int4{0, 0, 0, 0};
    __syncthreads();

    int4 d4, s4;
    bool act = (4 * t < n);
    if (act) {
        d4 = ((const int4*)(dst + base))[t];
        s4 = ((const int4*)(src + base))[t];
        atomicAdd(&lhist[d4.x >> 6], 1);
        atomicAdd(&lhist[d4.y >> 6], 1);
        atomicAdd(&lhist[d4.z >> 6], 1);
        atomicAdd(&lhist[d4.w >> 6], 1);
    }
    __syncthreads();

    int4 hv = ((const int4*)lhist)[t];
    int lsum = hv.x + hv.y + hv.z + hv.w;
    ws[t] = lsum; __syncthreads();
    #pragma unroll
    for (int off = 1; off < 256; off <<= 1) {
        int x = (t >= off) ? ws[t - off] : 0;
        __syncthreads(); ws[t] += x; __syncthreads();
    }
    int excl = ws[t] - lsum;
    int p0 = excl, p1 = p0 + hv.x, p2 = p1 + hv.y, p3 = p2 + hv.z;
    lcur[4 * t]     = p0;
    lcur[4 * t + 1] = p1;
    lcur[4 * t + 2] = p2;
    lcur[4 * t + 3] = p3;
    uint4 te;
    te.x = ((uint)p0 << 11) | (uint)hv.x;
    te.y = ((uint)p1 << 11) | (uint)hv.y;
    te.z = ((uint)p2 << 11) | (uint)hv.z;
    te.w = ((uint)p3 << 11) | (uint)hv.w;
    ((uint4*)(tab + (size_t)c * NBKT_PAD))[t] = te;
    __syncthreads();

    if (act) {
        int dd[4] = {d4.x, d4.y, d4.z, d4.w};
        int ss[4] = {s4.x, s4.y, s4.z, s4.w};
        #pragma unroll
        for (int u = 0; u < 4; ++u) {
            int b = dd[u] >> 6, dl = dd[u] & 63;
            int slot = atomicAdd(&lcur[b], 1);
            staged[slot] = ((uint)dl << 16) | (uint)ss[u];
        }
    }
    __syncthreads();
    #pragma unroll
    for (int k = 0; k < EPB / 256; ++k) {
        int i = k * 256 + t;
        if (i < n) binned[base + i] = staged[i];
    }
}

// ---------------------------------------------------------------------------
// K2: per-64-node-bucket sort. Gathers bucket edges from NCHUNK block-major
// runs via tab, stages in LDS, counting-sorts by dl with fused exp (f16),
// writes srcEx with x4-padded node segments; pad slots are DUMMY edges
// (src=0, ex=0) so aggc is tail-free. cntArr stores PADDED count.
// ---------------------------------------------------------------------------
__global__ __launch_bounds__(256) void k_sort(const uint* __restrict__ binned,
                                              const uint* __restrict__ tab,
                                              const float* __restrict__ sS,
                                              const float* __restrict__ sD,
                                              uint* __restrict__ srcEx,
                                              int* __restrict__ rowptrFine,
                                              int* __restrict__ cntArr) {
    __shared__ uint lstage[BCAP];          // 8 KB
    __shared__ uint lEdge[SSTRIDE];        // 8.75 KB
    __shared__ int lhist[64], lcur[64], ws[256];
    __shared__ float ldsD[64];
    __shared__ int sPtot;
    const int b = blockIdx.x, t = threadIdx.x;
    const int node = (b << 6) + t;
    if (t < 64) {
        lhist[t] = 0;
        ldsD[t] = (node < N_NODES) ? sD[node] : 0.f;
    }
    __syncthreads();

    // pass 1: walk my chunks' tab entries, count my edges
    uint runs[5];
    int nck = 0, myCnt = 0;
    for (int c = t; c < NCHUNK; c += 256) {
        uint e = tab[(size_t)c * NBKT_PAD + b];
        runs[nck++] = e;
        myCnt += (int)(e & 0x7FF);
    }
    ws[t] = myCnt; __syncthreads();
    #pragma unroll
    for (int off = 1; off < 256; off <<= 1) {
        int x = (t >= off) ? ws[t - off] : 0;
        __syncthreads(); ws[t] += x; __syncthreads();
    }
    int pos = ws[t] - myCnt;
    int n = ws[255];
    __syncthreads();

    // pass 2: gather my runs into lstage + dl histogram
    {
        int k = 0;
        for (int c = t; c < NCHUNK; c += 256, ++k) {
            uint e = runs[k];
            int cnt = (int)(e & 0x7FF);
            const uint* pB = binned + (size_t)c * EPB + (e >> 11);
            for (int i = 0; i < cnt; ++i) {
                uint w = pB[i];
                lstage[pos++] = w;
                atomicAdd(&lhist[w >> 16], 1);
            }
        }
    }
    __syncthreads();

    // pad-to-x4 scan over 64 nodes; zero-fill dummy pad slots
    int pc = 0;
    if (t < 64) { pc = (lhist[t] + 3) & ~3; ws[t] = pc; }
    __syncthreads();
    #pragma unroll
    for (int off = 1; off < 64; off <<= 1) {
        int x = 0;
        if (t < 64 && t >= off) x = ws[t - off];
        __syncthreads();
        if (t < 64) ws[t] += x;
        __syncthreads();
    }
    if (t < 64) {
        int pexcl = ws[t] - pc;
        lcur[t] = pexcl;
        for (int j = lhist[t]; j < pc; ++j) lEdge[pexcl + j] = 0;  // dummy: src=0, ex=0
        if (node < N_NODES) {
            rowptrFine[node] = b * SSTRIDE + pexcl;
            cntArr[node] = pc;            // padded count (multiple of 4)
        }
        if (t == 63) sPtot = ws[63];
    }
    __syncthreads();

    // permute + fused exp
    for (int i = t; i < n; i += 256) {
        uint w = lstage[i];
        int dl = (int)(w >> 16);
        int s  = (int)(w & 0xFFFF);
        float e = sS[s] + ldsD[dl];
        e = e > 0.f ? e : SLOPE * e;
        ushort exb = f32_f16(__expf(e));
        int slot = atomicAdd(&lcur[dl], 1);
        lEdge[slot] = ((w & 0xFFFFu) << 16) | (uint)exb;
    }
    __syncthreads();

    int ptot = sPtot;
    uint* dstp = srcEx + (size_t)b * SSTRIDE;
    for (int i = t; i < ptot; i += 256) dstp[i] = lEdge[i];
}

// ---------------------------------------------------------------------------
// K3: one wave per dst node, QUARTER-wave layout: 16 lanes/edge, lane covers
// 4 dims via one uint2 (8B) gather -> one gather instr serves 4 edges. Clean
// cnt4/4-iteration loop (dummy-padded, no tail); unroll-4 => 4 gathers in
// flight; 2-round shfl reduction; single coalesced float4 store per node.
// ---------------------------------------------------------------------------
__global__ __launch_bounds__(256) void k_aggc(const uint2* __restrict__ zrow,
                                              const uint* __restrict__ srcEx,
                                              const int* __restrict__ rowptr,
                                              const int* __restrict__ cntArr,
                                              float* __restrict__ out) {
    int node = blockIdx.x * 4 + (threadIdx.x >> 6);
    int lane = threadIdx.x & 63;
    int q = lane >> 4, ql = lane & 15;
    int beg = rowptr[node];
    int cnt4 = cntArr[node];
    float a0 = 0.f, a1 = 0.f, a2 = 0.f, a3 = 0.f, den = 0.f;
    #pragma unroll 4
    for (int i = 0; i < cnt4; i += 4) {
        uint w = srcEx[beg + i + q];
        uint2 zp = zrow[((w >> 16) << 4) + ql];
        float ex = f16_f32((ushort)(w & 0xFFFF));
        a0 += ex * f16_f32((ushort)(zp.x & 0xFFFF));
        a1 += ex * f16_f32((ushort)(zp.x >> 16));
        a2 += ex * f16_f32((ushort)(zp.y & 0xFFFF));
        a3 += ex * f16_f32((ushort)(zp.y >> 16));
        den += ex;
    }
    a0 += __shfl_xor(a0, 16); a0 += __shfl_xor(a0, 32);
    a1 += __shfl_xor(a1, 16); a1 += __shfl_xor(a1, 32);
    a2 += __shfl_xor(a2, 16); a2 += __shfl_xor(a2, 32);
    a3 += __shfl_xor(a3, 16); a3 += __shfl_xor(a3, 32);
    den += __shfl_xor(den, 16); den += __shfl_xor(den, 32);
    if (q == 0) {
        float inv = den > 0.f ? 1.f / den : 0.f;
        float r0 = a0 * inv, r1 = a1 * inv, r2 = a2 * inv, r3 = a3 * inv;
        r0 = r0 > 0.f ? r0 : expm1f(r0);
        r1 = r1 > 0.f ? r1 : expm1f(r1);
        r2 = r2 > 0.f ? r2 : expm1f(r2);
        r3 = r3 > 0.f ? r3 : expm1f(r3);
        float4 r = make_float4(r0, r1, r2, r3);
        ((float4*)out)[(size_t)node * 16 + ql] = r;
    }
}

static inline char* alignup(char* p) {
    return (char*)(((uintptr_t)p + 63) & ~(uintptr_t)63);
}

extern "C" void kernel_launch(void* const* d_in, const int* in_sizes, int n_in,
                              void* d_out, int out_size, void* d_ws, size_t ws_size,
                              hipStream_t stream) {
    const float* h     = (const float*)d_in[0];
    const float* Wfc   = (const float*)d_in[1];
    const float* Wattn = (const float*)d_in[2];
    const int*   src   = (const int*)d_in[3];
    const int*   dst   = (const int*)d_in[4];
    float* out = (float*)d_out;

    // workspace layout (64B-aligned regions)
    char* p = (char*)d_ws;
    uint*   binned  = (uint*)p;   p = alignup(p + (size_t)N_EDGES * 4);
    uint*   tab     = (uint*)p;   p = alignup(p + (size_t)NCHUNK * NBKT_PAD * 4);
    uint*   srcEx   = (uint*)p;   p = alignup(p + (size_t)NBKT * SSTRIDE * 4);
    int*    rowptrF = (int*)p;    p = alignup(p + (size_t)N_NODES * 4);
    int*    cntArr  = (int*)p;    p = alignup(p + (size_t)N_NODES * 4);
    float*  sS      = (float*)p;  p = alignup(p + (size_t)N_NODES * 4);
    float*  sD      = (float*)p;  p = alignup(p + (size_t)N_NODES * 4);
    ushort* Whi     = (ushort*)p; p = alignup(p + OUT_DIM * IN_DIM * 2);
    ushort* Wlo     = (ushort*)p; p = alignup(p + OUT_DIM * IN_DIM * 2);
    ushort* zh      = (ushort*)p;

    k_wprep<<<64, 256, 0, stream>>>(Wfc, Whi, Wlo);
    k_binmm<<<NCHUNK + NGEMMB, 256, 0, stream>>>(src, dst, h, Whi, Wlo, Wattn,
                                                 binned, tab, zh, sS, sD);
    k_sort<<<NBKT, 256, 0, stream>>>(binned, tab, sS, sD, srcEx, rowptrF, cntArr);
    k_aggc<<<N_NODES / 4, 256, 0, stream>>>((const uint2*)zh, srcEx, rowptrF, cntArr, out);
}

// Round 14
// 93.470 us; speedup vs baseline: 1.1838x; 1.1728x over previous
//
#include <hip/hip_runtime.h>
#include <math.h>

#define N_NODES 50000
#define N_EDGES 1200000
#define IN_DIM  256
#define OUT_DIM 64
#define SLOPE   0.2f
#define BNODES  64           // nodes per bucket: b = dst>>6, dl = dst&63
#define NBKT    782          // ceil(50000/64)
#define NBKT_PAD 1024
#define EPB     1024         // edges per k_bin chunk
#define NCHUNK  1172         // ceil(1200000/1024)
#define BCAP    2048         // max raw edges per bucket (mean 1536, +13 sigma)
#define SSTRIDE 2240         // padded srcEx stride per bucket (BCAP + 64*3, x4)

typedef unsigned int   uint;
typedef unsigned short ushort;
typedef float  f32x4  __attribute__((ext_vector_type(4)));
typedef short  short8 __attribute__((ext_vector_type(8)));

__device__ inline ushort bf16_rne(float f) {
    uint u = __float_as_uint(f);
    u += 0x7FFF + ((u >> 16) & 1);
    return (ushort)(u >> 16);
}
__device__ inline float bf16_f32(ushort s) {
    return __uint_as_float(((uint)s) << 16);
}
__device__ inline ushort f32_f16(float f) {
    _Float16 h = (_Float16)f;
    return __builtin_bit_cast(ushort, h);
}
__device__ inline float f16_f32(ushort u) {
    return (float)__builtin_bit_cast(_Float16, u);
}

// ---------------------------------------------------------------------------
// K0: blocks 0..NCHUNK-1: per-chunk bucket-grouping of 1024 edges (block-major
// output, NO global placement/atomics). binned[c*EPB+i] = (dl<<16)|src grouped
// by bucket; tab[c*1024+b] = (localOffset<<11)|count.
// Blocks NCHUNK..NCHUNK+63: W -> bf16 hi/lo prep.
// ---------------------------------------------------------------------------
__global__ __launch_bounds__(256) void k_binprep(const int* __restrict__ src,
                                                 const int* __restrict__ dst,
                                                 const float* __restrict__ Wfc,
                                                 ushort* __restrict__ Whi,
                                                 ushort* __restrict__ Wlo,
                                                 uint* __restrict__ binned,
                                                 uint* __restrict__ tab) {
    if (blockIdx.x >= NCHUNK) {
        int i = (blockIdx.x - NCHUNK) * 256 + threadIdx.x;
        float f = Wfc[i];
        ushort hi = bf16_rne(f);
        Whi[i] = hi;
        Wlo[i] = bf16_rne(f - bf16_f32(hi));
        return;
    }
    __shared__ uint staged[EPB];           // 4 KB
    __shared__ int lhist[NBKT_PAD];        // 4 KB
    __shared__ int lcur[NBKT_PAD];         // 4 KB
    __shared__ int ws[256];
    const int t = threadIdx.x;
    const int c = blockIdx.x;
    const int base = c * EPB;
    const int n = min(EPB, N_EDGES - base);   // multiple of 4

    ((int4*)lhist)[t] = int4{0, 0, 0, 0};
    __syncthreads();

    int4 d4, s4;
    bool act = (4 * t < n);
    if (act) {
        d4 = ((const int4*)(dst + base))[t];
        s4 = ((const int4*)(src + base))[t];
        atomicAdd(&lhist[d4.x >> 6], 1);
        atomicAdd(&lhist[d4.y >> 6], 1);
        atomicAdd(&lhist[d4.z >> 6], 1);
        atomicAdd(&lhist[d4.w >> 6], 1);
    }
    __syncthreads();

    int4 hv = ((const int4*)lhist)[t];
    int lsum = hv.x + hv.y + hv.z + hv.w;
    ws[t] = lsum; __syncthreads();
    #pragma unroll
    for (int off = 1; off < 256; off <<= 1) {
        int x = (t >= off) ? ws[t - off] : 0;
        __syncthreads(); ws[t] += x; __syncthreads();
    }
    int excl = ws[t] - lsum;
    int p0 = excl, p1 = p0 + hv.x, p2 = p1 + hv.y, p3 = p2 + hv.z;
    lcur[4 * t]     = p0;
    lcur[4 * t + 1] = p1;
    lcur[4 * t + 2] = p2;
    lcur[4 * t + 3] = p3;
    uint4 te;
    te.x = ((uint)p0 << 11) | (uint)hv.x;
    te.y = ((uint)p1 << 11) | (uint)hv.y;
    te.z = ((uint)p2 << 11) | (uint)hv.z;
    te.w = ((uint)p3 << 11) | (uint)hv.w;
    ((uint4*)(tab + (size_t)c * NBKT_PAD))[t] = te;
    __syncthreads();

    if (act) {
        int dd[4] = {d4.x, d4.y, d4.z, d4.w};
        int ss[4] = {s4.x, s4.y, s4.z, s4.w};
        #pragma unroll
        for (int u = 0; u < 4; ++u) {
            int b = dd[u] >> 6, dl = dd[u] & 63;
            int slot = atomicAdd(&lcur[b], 1);
            staged[slot] = ((uint)dl << 16) | (uint)ss[u];
        }
    }
    __syncthreads();
    #pragma unroll
    for (int k = 0; k < EPB / 256; ++k) {
        int i = k * 256 + t;
        if (i < n) binned[base + i] = staged[i];
    }
}

// ---------------------------------------------------------------------------
// K1: z = h @ W^T via mfma_f32_16x16x32_bf16. A = bf16(h) hi only; W is
// precomputed hi+lo => 2 MFMAs per (ks,n). One wave / 16 nodes, no LDS.
// Fused sS/sD. z stored f16.
// ---------------------------------------------------------------------------
__global__ __launch_bounds__(64) void k_gemm(const float* __restrict__ h,
                                             const ushort* __restrict__ Whi,
                                             const ushort* __restrict__ Wlo,
                                             const float* __restrict__ Wattn,
                                             ushort* __restrict__ zh,
                                             float* __restrict__ sS,
                                             float* __restrict__ sD) {
    const int l   = threadIdx.x;
    const int r16 = l & 15;
    const int g   = l >> 4;
    const int base = blockIdx.x * 16;

    const float*  ha = h   + (size_t)(base + r16) * IN_DIM + g * 8;
    const ushort* wh = Whi + (size_t)r16 * IN_DIM + g * 8;
    const ushort* wl = Wlo + (size_t)r16 * IN_DIM + g * 8;

    f32x4 c[4] = {{0,0,0,0},{0,0,0,0},{0,0,0,0},{0,0,0,0}};

    #pragma unroll
    for (int ks = 0; ks < 8; ++ks) {
        float4 a0 = *(const float4*)(ha + ks * 32);
        float4 a1 = *(const float4*)(ha + ks * 32 + 4);
        float af[8] = {a0.x, a0.y, a0.z, a0.w, a1.x, a1.y, a1.z, a1.w};
        short8 ahi;
        #pragma unroll
        for (int i = 0; i < 8; ++i) ahi[i] = (short)bf16_rne(af[i]);
        #pragma unroll
        for (int n = 0; n < 4; ++n) {
            short8 bh = *(const short8*)(wh + n * 16 * IN_DIM + ks * 32);
            short8 bl = *(const short8*)(wl + n * 16 * IN_DIM + ks * 32);
            c[n] = __builtin_amdgcn_mfma_f32_16x16x32_bf16(ahi, bh, c[n], 0, 0, 0);
            c[n] = __builtin_amdgcn_mfma_f32_16x16x32_bf16(ahi, bl, c[n], 0, 0, 0);
        }
    }

    float aSv[4], aDv[4];
    #pragma unroll
    for (int n = 0; n < 4; ++n) {
        aSv[n] = Wattn[n * 16 + r16];
        aDv[n] = Wattn[OUT_DIM + n * 16 + r16];
    }
    #pragma unroll
    for (int r = 0; r < 4; ++r) {
        int node = base + g * 4 + r;
        float ss = 0.f, sd = 0.f;
        #pragma unroll
        for (int n = 0; n < 4; ++n) {
            float v = c[n][r];
            zh[(size_t)node * OUT_DIM + n * 16 + r16] = f32_f16(v);
            ss += v * aSv[n];
            sd += v * aDv[n];
        }
        ss += __shfl_xor(ss, 1); ss += __shfl_xor(ss, 2);
        ss += __shfl_xor(ss, 4); ss += __shfl_xor(ss, 8);
        sd += __shfl_xor(sd, 1); sd += __shfl_xor(sd, 2);
        sd += __shfl_xor(sd, 4); sd += __shfl_xor(sd, 8);
        if (r16 == 0) { sS[node] = ss; sD[node] = sd; }
    }
}

// ---------------------------------------------------------------------------
// K2: per-64-node-bucket sort. Gathers bucket edges from NCHUNK block-major
// runs via tab, stages in LDS, counting-sorts by dl with fused exp (f16),
// writes srcEx with x4-padded node segments; pad slots are DUMMY edges
// (src=0, ex=0) so aggc is tail-free. cntArr stores PADDED count.
// ---------------------------------------------------------------------------
__global__ __launch_bounds__(256) void k_sort(const uint* __restrict__ binned,
                                              const uint* __restrict__ tab,
                                              const float* __restrict__ sS,
                                              const float* __restrict__ sD,
                                              uint* __restrict__ srcEx,
                                              int* __restrict__ rowptrFine,
                                              int* __restrict__ cntArr) {
    __shared__ uint lstage[BCAP];          // 8 KB
    __shared__ uint lEdge[SSTRIDE];        // 8.75 KB
    __shared__ int lhist[64], lcur[64], ws[256];
    __shared__ float ldsD[64];
    __shared__ int sPtot;
    const int b = blockIdx.x, t = threadIdx.x;
    const int node = (b << 6) + t;
    if (t < 64) {
        lhist[t] = 0;
        ldsD[t] = (node < N_NODES) ? sD[node] : 0.f;
    }
    __syncthreads();

    // pass 1: walk my chunks' tab entries, count my edges
    uint runs[5];
    int nck = 0, myCnt = 0;
    for (int c = t; c < NCHUNK; c += 256) {
        uint e = tab[(size_t)c * NBKT_PAD + b];
        runs[nck++] = e;
        myCnt += (int)(e & 0x7FF);
    }
    ws[t] = myCnt; __syncthreads();
    #pragma unroll
    for (int off = 1; off < 256; off <<= 1) {
        int x = (t >= off) ? ws[t - off] : 0;
        __syncthreads(); ws[t] += x; __syncthreads();
    }
    int pos = ws[t] - myCnt;
    int n = ws[255];
    __syncthreads();

    // pass 2: gather my runs into lstage + dl histogram
    {
        int k = 0;
        for (int c = t; c < NCHUNK; c += 256, ++k) {
            uint e = runs[k];
            int cnt = (int)(e & 0x7FF);
            const uint* pB = binned + (size_t)c * EPB + (e >> 11);
            for (int i = 0; i < cnt; ++i) {
                uint w = pB[i];
                lstage[pos++] = w;
                atomicAdd(&lhist[w >> 16], 1);
            }
        }
    }
    __syncthreads();

    // pad-to-x4 scan over 64 nodes; zero-fill dummy pad slots
    int pc = 0;
    if (t < 64) { pc = (lhist[t] + 3) & ~3; ws[t] = pc; }
    __syncthreads();
    #pragma unroll
    for (int off = 1; off < 64; off <<= 1) {
        int x = 0;
        if (t < 64 && t >= off) x = ws[t - off];
        __syncthreads();
        if (t < 64) ws[t] += x;
        __syncthreads();
    }
    if (t < 64) {
        int pexcl = ws[t] - pc;
        lcur[t] = pexcl;
        for (int j = lhist[t]; j < pc; ++j) lEdge[pexcl + j] = 0;  // dummy: src=0, ex=0
        if (node < N_NODES) {
            rowptrFine[node] = b * SSTRIDE + pexcl;
            cntArr[node] = pc;            // padded count (multiple of 4)
        }
        if (t == 63) sPtot = ws[63];
    }
    __syncthreads();

    // permute + fused exp
    for (int i = t; i < n; i += 256) {
        uint w = lstage[i];
        int dl = (int)(w >> 16);
        int s  = (int)(w & 0xFFFF);
        float e = sS[s] + ldsD[dl];
        e = e > 0.f ? e : SLOPE * e;
        ushort exb = f32_f16(__expf(e));
        int slot = atomicAdd(&lcur[dl], 1);
        lEdge[slot] = ((w & 0xFFFFu) << 16) | (uint)exb;
    }
    __syncthreads();

    int ptot = sPtot;
    uint* dstp = srcEx + (size_t)b * SSTRIDE;
    for (int i = t; i < ptot; i += 256) dstp[i] = lEdge[i];
}

// ---------------------------------------------------------------------------
// K3: one wave per dst node, QUARTER-wave layout: 16 lanes/edge, lane covers
// 4 dims via one uint2 (8B) gather -> one gather instr serves 4 edges. Clean
// cnt4/4-iteration loop (dummy-padded, no tail); unroll-4 => 4 gathers in
// flight; 2-round shfl reduction; single coalesced float4 store per node.
// ---------------------------------------------------------------------------
__global__ __launch_bounds__(256) void k_aggc(const uint2* __restrict__ zrow,
                                              const uint* __restrict__ srcEx,
                                              const int* __restrict__ rowptr,
                                              const int* __restrict__ cntArr,
                                              float* __restrict__ out) {
    int node = blockIdx.x * 4 + (threadIdx.x >> 6);
    int lane = threadIdx.x & 63;
    int q = lane >> 4, ql = lane & 15;
    int beg = rowptr[node];
    int cnt4 = cntArr[node];
    float a0 = 0.f, a1 = 0.f, a2 = 0.f, a3 = 0.f, den = 0.f;
    #pragma unroll 4
    for (int i = 0; i < cnt4; i += 4) {
        uint w = srcEx[beg + i + q];
        uint2 zp = zrow[((w >> 16) << 4) + ql];
        float ex = f16_f32((ushort)(w & 0xFFFF));
        a0 += ex * f16_f32((ushort)(zp.x & 0xFFFF));
        a1 += ex * f16_f32((ushort)(zp.x >> 16));
        a2 += ex * f16_f32((ushort)(zp.y & 0xFFFF));
        a3 += ex * f16_f32((ushort)(zp.y >> 16));
        den += ex;
    }
    a0 += __shfl_xor(a0, 16); a0 += __shfl_xor(a0, 32);
    a1 += __shfl_xor(a1, 16); a1 += __shfl_xor(a1, 32);
    a2 += __shfl_xor(a2, 16); a2 += __shfl_xor(a2, 32);
    a3 += __shfl_xor(a3, 16); a3 += __shfl_xor(a3, 32);
    den += __shfl_xor(den, 16); den += __shfl_xor(den, 32);
    if (q == 0) {
        float inv = den > 0.f ? 1.f / den : 0.f;
        float r0 = a0 * inv, r1 = a1 * inv, r2 = a2 * inv, r3 = a3 * inv;
        r0 = r0 > 0.f ? r0 : expm1f(r0);
        r1 = r1 > 0.f ? r1 : expm1f(r1);
        r2 = r2 > 0.f ? r2 : expm1f(r2);
        r3 = r3 > 0.f ? r3 : expm1f(r3);
        float4 r = make_float4(r0, r1, r2, r3);
        ((float4*)out)[(size_t)node * 16 + ql] = r;
    }
}

static inline char* alignup(char* p) {
    return (char*)(((uintptr_t)p + 63) & ~(uintptr_t)63);
}

extern "C" void kernel_launch(void* const* d_in, const int* in_sizes, int n_in,
                              void* d_out, int out_size, void* d_ws, size_t ws_size,
                              hipStream_t stream) {
    const float* h     = (const float*)d_in[0];
    const float* Wfc   = (const float*)d_in[1];
    const float* Wattn = (const float*)d_in[2];
    const int*   src   = (const int*)d_in[3];
    const int*   dst   = (const int*)d_in[4];
    float* out = (float*)d_out;

    // workspace layout (64B-aligned regions)
    char* p = (char*)d_ws;
    uint*   binned  = (uint*)p;   p = alignup(p + (size_t)N_EDGES * 4);
    uint*   tab     = (uint*)p;   p = alignup(p + (size_t)NCHUNK * NBKT_PAD * 4);
    uint*   srcEx   = (uint*)p;   p = alignup(p + (size_t)NBKT * SSTRIDE * 4);
    int*    rowptrF = (int*)p;    p = alignup(p + (size_t)N_NODES * 4);
    int*    cntArr  = (int*)p;    p = alignup(p + (size_t)N_NODES * 4);
    float*  sS      = (float*)p;  p = alignup(p + (size_t)N_NODES * 4);
    float*  sD      = (float*)p;  p = alignup(p + (size_t)N_NODES * 4);
    ushort* Whi     = (ushort*)p; p = alignup(p + OUT_DIM * IN_DIM * 2);
    ushort* Wlo     = (ushort*)p; p = alignup(p + OUT_DIM * IN_DIM * 2);
    ushort* zh      = (ushort*)p;

    k_binprep<<<NCHUNK + 64, 256, 0, stream>>>(src, dst, Wfc, Whi, Wlo, binned, tab);
    k_gemm<<<N_NODES / 16, 64, 0, stream>>>(h, Whi, Wlo, Wattn, zh, sS, sD);
    k_sort<<<NBKT, 256, 0, stream>>>(binned, tab, sS, sD, srcEx, rowptrF, cntArr);
    k_aggc<<<N_NODES / 4, 256, 0, stream>>>((const uint2*)zh, srcEx, rowptrF, cntArr, out);
}